// Round 6
// baseline (3897.777 us; speedup 1.0000x reference)
//
#include <hip/hip_runtime.h>

// QLinear: y[b,s,o] = sum_i x[b,s,i] * W_q[o,i] * scale[o]
#define M_DIM 8192    // BATCH*SEQ
#define N_DIM 11008   // OUT_F
#define K_DIM 4096    // IN_F

#define BM 256
#define BN 256
#define BK 64
#define NT (K_DIM / BK)            // 64 K-tiles
#define NBN (N_DIM / BN)           // 43
#define NWG ((M_DIM / BM) * NBN)   // 1376 (divisible by 8)

typedef __bf16 bf16x8 __attribute__((ext_vector_type(8)));
typedef float f32x4 __attribute__((ext_vector_type(4)));
typedef unsigned short ushort8 __attribute__((ext_vector_type(8)));

__device__ __forceinline__ unsigned short f2bf(float f) {
  unsigned u = __builtin_bit_cast(unsigned, f);
  u += 0x7fffu + ((u >> 16) & 1u);
  return (unsigned short)(u >> 16);
}

__device__ __forceinline__ void async_copy16(const void* g, void* l) {
  __builtin_amdgcn_global_load_lds(
      (const __attribute__((address_space(1))) void*)g,
      (__attribute__((address_space(3))) void*)l, 16, 0, 0);
}

// ---- conversion kernels ----
__global__ __launch_bounds__(256) void cvt_x_kernel(const float* __restrict__ in,
                                                    unsigned short* __restrict__ outp) {
  const int idx = blockIdx.x * 256 + threadIdx.x;
  const float4* in4 = (const float4*)in;
  float4 a = in4[2 * idx], b = in4[2 * idx + 1];
  ushort8 o;
  o[0] = f2bf(a.x); o[1] = f2bf(a.y); o[2] = f2bf(a.z); o[3] = f2bf(a.w);
  o[4] = f2bf(b.x); o[5] = f2bf(b.y); o[6] = f2bf(b.z); o[7] = f2bf(b.w);
  ((ushort8*)outp)[idx] = o;
}

__global__ __launch_bounds__(256) void cvt_w_kernel(const int* __restrict__ in,
                                                    unsigned short* __restrict__ outp) {
  const int idx = blockIdx.x * 256 + threadIdx.x;
  const int4* in4 = (const int4*)in;
  int4 a = in4[2 * idx], b = in4[2 * idx + 1];
  ushort8 o;  // values 0..15: exact in bf16
  o[0] = f2bf((float)a.x); o[1] = f2bf((float)a.y);
  o[2] = f2bf((float)a.z); o[3] = f2bf((float)a.w);
  o[4] = f2bf((float)b.x); o[5] = f2bf((float)b.y);
  o[6] = f2bf((float)b.z); o[7] = f2bf((float)b.w);
  ((ushort8*)outp)[idx] = o;
}

// Stage one 128x64 half-tile (16 KiB): linear LDS dest, inverse-swizzled
// global source (rule #21 both-sides swizzle). 2 gload_lds -> vmcnt +2.
__device__ __forceinline__ void stage_half(const unsigned short* __restrict__ P,
                                           int grow0, int k0, char* dest, int tid) {
  const int rl = tid >> 3;                            // 0..63
  const int kb = ((tid & 7) * 16) ^ ((rl & 7) << 4);  // pre-swizzled k-byte
  async_copy16(&P[(size_t)(grow0 + rl) * K_DIM + k0 + (kb >> 1)], dest + tid * 16);
  async_copy16(&P[(size_t)(grow0 + 64 + rl) * K_DIM + k0 + (kb >> 1)],
               dest + 8192 + tid * 16);
}

// Read macros (capture lrow/kg16/swz/brow0 from scope); all indices static.
#define READ_A4(DST, BUF, ROFF)                                               \
  _Pragma("unroll") for (int kk = 0; kk < 2; ++kk)                            \
  _Pragma("unroll") for (int m = 0; m < 4; ++m)                               \
    DST[kk][m] = *(const bf16x8*)((BUF) + ((ROFF) + m * 16 + lrow) * 128 +    \
                                  ((kk * 64 + kg16) ^ swz));

#define READ_B2(DST, BUF, COFF)                                               \
  _Pragma("unroll") for (int kk = 0; kk < 2; ++kk)                            \
  _Pragma("unroll") for (int n = 0; n < 2; ++n)                               \
    DST[kk][n] = *(const bf16x8*)((BUF) + (brow0 + (COFF) + n * 16) * 128 +   \
                                  ((kk * 64 + kg16) ^ swz));

#define MFMA_Q(AF, BF, MB, NB)                                                \
  __builtin_amdgcn_s_setprio(1);                                              \
  _Pragma("unroll") for (int kk = 0; kk < 2; ++kk)                            \
  _Pragma("unroll") for (int m = 0; m < 4; ++m)                               \
  _Pragma("unroll") for (int n = 0; n < 2; ++n)                               \
    acc[(MB) + m][(NB) + n] = __builtin_amdgcn_mfma_f32_16x16x32_bf16(        \
        AF[kk][m], BF[kk][n], acc[(MB) + m][(NB) + n], 0, 0, 0);              \
  __builtin_amdgcn_s_setprio(0);

// One K-tile, 4 phases. Reads are pipelined ONE PHASE AHEAD:
//  P1: read bh(t)        | stage Ah0(t+1) | MFMA q1 = af0 x bl   | bar
//  P2: read af1(t)       | stage Ah1(t+1) | MFMA q2 = af0 x bh   | bar
//  P3:                   | stage Bh0(t+2) | MFMA q3 = af1 x bl   | vmcnt | bar
//  P4: read af0n,bln(t+1)| stage Bh1(t+2) | MFMA q4 = af1 x bh   | bar
#define TILE_BODY(T, AF0, BL, AF0N, BLN)                                       \
  {                                                                            \
    const int cur_ = (T) & 1;                                                  \
    const char* Abuf_ = smw + cur_ * 65536 + wr * 16384;                       \
    const char* Bbuf_ = smw + cur_ * 65536 + 32768 + (wc >> 1) * 16384;        \
    const char* AbufN_ = smw + (cur_ ^ 1) * 65536 + wr * 16384;                \
    const char* BbufN_ = smw + (cur_ ^ 1) * 65536 + 32768 + (wc >> 1) * 16384; \
    char* nbA_ = smw + (cur_ ^ 1) * 65536;                                     \
    char* cbB_ = smw + cur_ * 65536 + 32768;                                   \
    /* P1 */                                                                   \
    READ_B2(bh, Bbuf_, 32);                                                    \
    if ((T) + 1 < NT) stage_half(A, bm, ((T) + 1) * BK, nbA_, tid);            \
    __builtin_amdgcn_sched_barrier(0);                                         \
    MFMA_Q(AF0, BL, 0, 0);                                                     \
    __builtin_amdgcn_s_barrier();                                              \
    /* P2 */                                                                   \
    READ_A4(af1, Abuf_, 64);                                                   \
    if ((T) + 1 < NT) stage_half(A, bm + 128, ((T) + 1) * BK, nbA_ + 16384, tid); \
    __builtin_amdgcn_sched_barrier(0);                                         \
    MFMA_Q(AF0, bh, 0, 2);                                                     \
    __builtin_amdgcn_s_barrier();                                              \
    /* P3 */                                                                   \
    if ((T) + 2 < NT) stage_half(B, bn, ((T) + 2) * BK, cbB_, tid);            \
    __builtin_amdgcn_sched_barrier(0);                                         \
    MFMA_Q(af1, BL, 4, 0);                                                     \
    if ((T) + 2 < NT) {                                                        \
      asm volatile("s_waitcnt vmcnt(2)" ::: "memory");  /* Ah(t+1) landed */   \
    } else {                                                                   \
      asm volatile("s_waitcnt vmcnt(0)" ::: "memory");  /* tail drain */       \
    }                                                                          \
    __builtin_amdgcn_s_barrier();                                              \
    /* P4 */                                                                   \
    if ((T) + 1 < NT) { READ_A4(AF0N, AbufN_, 0); READ_B2(BLN, BbufN_, 0); }   \
    if ((T) + 2 < NT) stage_half(B, bn + 128, ((T) + 2) * BK, cbB_ + 16384, tid); \
    __builtin_amdgcn_sched_barrier(0);                                         \
    MFMA_Q(af1, bh, 4, 2);                                                     \
    __builtin_amdgcn_s_barrier();                                              \
  }

// ---- main GEMM: 256x256, BK=64, 8 waves, phase-pipelined reads ----
__global__ __launch_bounds__(512, 2) void gemm_bf16(
    const unsigned short* __restrict__ A, const unsigned short* __restrict__ B,
    const float* __restrict__ scale, float* __restrict__ out) {
  __shared__ __align__(16) unsigned short sm[65536];  // 128 KiB, 2 buffers
  char* smw = (char*)sm;

  const int tid = threadIdx.x;
  const int lane = tid & 63;
  const int wv = tid >> 6;
  const int wr = wv >> 2, wc = wv & 3;   // 2x4 wave grid, 128x64 out/wave
  const int lrow = lane & 15, kg = lane >> 4;
  const int kg16 = kg * 16;
  const int swz = (lrow & 7) << 4;       // read-side XOR key (bytes)

  int id = blockIdx.x;                   // T1: bijective XCD swizzle
  id = (id & 7) * (NWG / 8) + (id >> 3);
  const int bn = (id % NBN) * BN;
  const int bm = (id / NBN) * BM;

  const int brow0 = (wc & 1) * 64 + lrow;  // B row within its half

  f32x4 acc[8][4] = {};
  bf16x8 af0X[2][4], blX[2][2], af0Y[2][4], blY[2][2];
  bf16x8 af1[2][4], bh[2][2];

  // prologue: tile0 full (8 loads) + tile1 B-halves (4 loads);
  // vmcnt BEFORE barrier (cross-wave visibility), then first r1 reads.
  stage_half(A, bm,       0, smw,         tid);
  stage_half(A, bm + 128, 0, smw + 16384, tid);
  stage_half(B, bn,       0, smw + 32768, tid);
  stage_half(B, bn + 128, 0, smw + 49152, tid);
  stage_half(B, bn,       BK, smw + 65536 + 32768, tid);
  stage_half(B, bn + 128, BK, smw + 65536 + 49152, tid);
  asm volatile("s_waitcnt vmcnt(4)" ::: "memory");  // tile0's 8 landed
  __builtin_amdgcn_s_barrier();
  {
    const char* Abuf0 = smw + wr * 16384;
    const char* Bbuf0 = smw + 32768 + (wc >> 1) * 16384;
    READ_A4(af0X, Abuf0, 0);
    READ_B2(blX, Bbuf0, 0);
  }

#pragma unroll 1
  for (int tt = 0; tt < NT; tt += 2) {
    TILE_BODY(tt,     af0X, blX, af0Y, blY);
    TILE_BODY(tt + 1, af0Y, blY, af0X, blX);
  }

  // epilogue: C/D layout col=lane&15, row=(lane>>4)*4+r  [m89-verified]
  const int orow = bm + wr * 128 + kg * 4;
  const int ocol = bn + wc * 64 + lrow;
#pragma unroll
  for (int n = 0; n < 4; ++n) {
    const float s = scale[ocol + n * 16];
#pragma unroll
    for (int m = 0; m < 8; ++m) {
#pragma unroll
      for (int r = 0; r < 4; ++r)
        out[(size_t)(orow + m * 16 + r) * N_DIM + ocol + n * 16] =
            acc[m][n][r] * s;
    }
  }
}

// ---- fallback (only if ws too small): fp32 LDS-tiled, correct but slow ----
__global__ __launch_bounds__(256) void gemm_fallback(
    const float* __restrict__ X, const int* __restrict__ Wq,
    const float* __restrict__ scale, float* __restrict__ out) {
  __shared__ float Xs[64][17];
  __shared__ float Ws[64][17];
  const int tid = threadIdx.x;
  const int tn = blockIdx.x % (N_DIM / 64);
  const int tm = blockIdx.x / (N_DIM / 64);
  const int tr = tid >> 4, tc = tid & 15;
  float acc[4][4] = {};
  for (int k0 = 0; k0 < K_DIM; k0 += 16) {
#pragma unroll
    for (int i = 0; i < 4; ++i) {
      int idx = tid + i * 256;
      int r = idx >> 4, c = idx & 15;
      Xs[r][c] = X[(size_t)(tm * 64 + r) * K_DIM + k0 + c];
      Ws[r][c] = (float)Wq[(size_t)(tn * 64 + r) * K_DIM + k0 + c];
    }
    __syncthreads();
#pragma unroll
    for (int kk = 0; kk < 16; ++kk)
#pragma unroll
      for (int i = 0; i < 4; ++i) {
        float a = Xs[tr * 4 + i][kk];
#pragma unroll
        for (int j = 0; j < 4; ++j) acc[i][j] += a * Ws[tc * 4 + j][kk];
      }
    __syncthreads();
  }
#pragma unroll
  for (int i = 0; i < 4; ++i)
#pragma unroll
    for (int j = 0; j < 4; ++j) {
      int row = tm * 64 + tr * 4 + i, col = tn * 64 + tc * 4 + j;
      out[(size_t)row * N_DIM + col] = acc[i][j] * scale[col];
    }
}

extern "C" void kernel_launch(void* const* d_in, const int* in_sizes, int n_in,
                              void* d_out, int out_size, void* d_ws, size_t ws_size,
                              hipStream_t stream) {
  const float* x = (const float*)d_in[0];
  const int* Wq = (const int*)d_in[1];
  const float* scale = (const float*)d_in[2];
  float* out = (float*)d_out;

  const size_t XN = (size_t)M_DIM * K_DIM;
  const size_t WN = (size_t)N_DIM * K_DIM;
  const size_t need = (XN + WN) * sizeof(unsigned short);

  if (ws_size >= need) {
    unsigned short* xbf = (unsigned short*)d_ws;
    unsigned short* wbf = xbf + XN;
    cvt_x_kernel<<<(unsigned)(XN / 2048), 256, 0, stream>>>(x, xbf);
    cvt_w_kernel<<<(unsigned)(WN / 2048), 256, 0, stream>>>(Wq, wbf);
    gemm_bf16<<<NWG, 512, 0, stream>>>(xbf, wbf, scale, out);
  } else {
    gemm_fallback<<<(N_DIM / 64) * (M_DIM / 64), 256, 0, stream>>>(x, Wq, scale, out);
  }
}

// Round 8
// 766.113 us; speedup vs baseline: 5.0877x; 5.0877x over previous
//
#include <hip/hip_runtime.h>

// QLinear: y[b,s,o] = sum_i x[b,s,i] * W_q[o,i] * scale[o]
#define M_DIM 8192    // BATCH*SEQ
#define N_DIM 11008   // OUT_F
#define K_DIM 4096    // IN_F

#define BM 256
#define BN 256
#define BK 64
#define NT (K_DIM / BK)            // 64 K-tiles
#define NBN (N_DIM / BN)           // 43
#define NWG ((M_DIM / BM) * NBN)   // 1376 (divisible by 8)

typedef __bf16 bf16x8 __attribute__((ext_vector_type(8)));
typedef float f32x4 __attribute__((ext_vector_type(4)));
typedef unsigned short ushort8 __attribute__((ext_vector_type(8)));

__device__ __forceinline__ unsigned short f2bf(float f) {
  unsigned u = __builtin_bit_cast(unsigned, f);
  u += 0x7fffu + ((u >> 16) & 1u);
  return (unsigned short)(u >> 16);
}

__device__ __forceinline__ void async_copy16(const void* g, void* l) {
  __builtin_amdgcn_global_load_lds(
      (const __attribute__((address_space(1))) void*)g,
      (__attribute__((address_space(3))) void*)l, 16, 0, 0);
}

// ---- conversion kernels ----
__global__ __launch_bounds__(256) void cvt_x_kernel(const float* __restrict__ in,
                                                    unsigned short* __restrict__ outp) {
  const int idx = blockIdx.x * 256 + threadIdx.x;
  const float4* in4 = (const float4*)in;
  float4 a = in4[2 * idx], b = in4[2 * idx + 1];
  ushort8 o;
  o[0] = f2bf(a.x); o[1] = f2bf(a.y); o[2] = f2bf(a.z); o[3] = f2bf(a.w);
  o[4] = f2bf(b.x); o[5] = f2bf(b.y); o[6] = f2bf(b.z); o[7] = f2bf(b.w);
  ((ushort8*)outp)[idx] = o;
}

__global__ __launch_bounds__(256) void cvt_w_kernel(const int* __restrict__ in,
                                                    unsigned short* __restrict__ outp) {
  const int idx = blockIdx.x * 256 + threadIdx.x;
  const int4* in4 = (const int4*)in;
  int4 a = in4[2 * idx], b = in4[2 * idx + 1];
  ushort8 o;  // values 0..15: exact in bf16
  o[0] = f2bf((float)a.x); o[1] = f2bf((float)a.y);
  o[2] = f2bf((float)a.z); o[3] = f2bf((float)a.w);
  o[4] = f2bf((float)b.x); o[5] = f2bf((float)b.y);
  o[6] = f2bf((float)b.z); o[7] = f2bf((float)b.w);
  ((ushort8*)outp)[idx] = o;
}

// Stage one 128x64 half-tile (16 KiB): linear LDS dest, inverse-swizzled
// global source (rule #21 both-sides swizzle). 2 gload_lds -> vmcnt +2.
__device__ __forceinline__ void stage_half(const unsigned short* __restrict__ P,
                                           int grow0, int k0, char* dest, int tid) {
  const int rl = tid >> 3;                            // 0..63
  const int kb = ((tid & 7) * 16) ^ ((rl & 7) << 4);  // pre-swizzled k-byte
  async_copy16(&P[(size_t)(grow0 + rl) * K_DIM + k0 + (kb >> 1)], dest + tid * 16);
  async_copy16(&P[(size_t)(grow0 + 64 + rl) * K_DIM + k0 + (kb >> 1)],
               dest + 8192 + tid * 16);
}

// Read macros (capture lrow/kg16/swz/brow0 from scope); all indices static.
#define READ_A4(DST, BUF, ROFF)                                               \
  _Pragma("unroll") for (int kk = 0; kk < 2; ++kk)                            \
  _Pragma("unroll") for (int m = 0; m < 4; ++m)                               \
    DST[kk][m] = *(const bf16x8*)((BUF) + ((ROFF) + m * 16 + lrow) * 128 +    \
                                  ((kk * 64 + kg16) ^ swz));

#define READ_B2(DST, BUF, COFF)                                               \
  _Pragma("unroll") for (int kk = 0; kk < 2; ++kk)                            \
  _Pragma("unroll") for (int n = 0; n < 2; ++n)                               \
    DST[kk][n] = *(const bf16x8*)((BUF) + (brow0 + (COFF) + n * 16) * 128 +   \
                                  ((kk * 64 + kg16) ^ swz));

#define MFMA_Q(AF, BF, MB, NB)                                                \
  __builtin_amdgcn_s_setprio(1);                                              \
  _Pragma("unroll") for (int kk = 0; kk < 2; ++kk)                            \
  _Pragma("unroll") for (int m = 0; m < 4; ++m)                               \
  _Pragma("unroll") for (int n = 0; n < 2; ++n)                               \
    acc[(MB) + m][(NB) + n] = __builtin_amdgcn_mfma_f32_16x16x32_bf16(        \
        AF[kk][m], BF[kk][n], acc[(MB) + m][(NB) + n], 0, 0, 0);              \
  __builtin_amdgcn_s_setprio(0);

// ---- main GEMM: 256x256, BK=64, 8 waves, 4-phase/K-tile.
// Staging is staggered so that ONE vmcnt(4) per tile (at P4-end, before the
// boundary barrier) certifies ALL FOUR halves of tile t+1 before any wave
// reads them at P1(t+1) — fixes R7's wave-partition race:
//   P1(t): stage A0(t+1)   P2(t): stage A1(t+1)
//   P3(t): stage B0(t+2)   P4(t): stage B1(t+2)
// At cert(t): outstanding = B0,B1(t+2) = 4 loads -> vmcnt(4) retires
// A1(t+1) and older. vmcnt never 0 except the t=NT-2 tail.
// WAR: B(t+2) overwrites buf[cur] B-regions only after P2's lgkm+barrier
// retired all bl/bh reads; A(t+1) goes to buf[cur^1] (last read tile t-1).
__global__ __launch_bounds__(512, 1) void gemm_bf16(
    const unsigned short* __restrict__ A, const unsigned short* __restrict__ B,
    const float* __restrict__ scale, float* __restrict__ out) {
  __shared__ __align__(16) unsigned short sm[65536];  // 128 KiB, 2 buffers
  char* smw = (char*)sm;

  const int tid = threadIdx.x;
  const int lane = tid & 63;
  const int wv = tid >> 6;
  const int wr = wv >> 2, wc = wv & 3;   // 2x4 wave grid, 128x64 out/wave
  const int lrow = lane & 15, kg = lane >> 4;
  const int kg16 = kg * 16;
  const int swz = (lrow & 7) << 4;       // read-side XOR key (bytes)

  int id = blockIdx.x;                   // T1: bijective XCD swizzle
  id = (id & 7) * (NWG / 8) + (id >> 3);
  const int bn = (id % NBN) * BN;
  const int bm = (id / NBN) * BM;

  const int brow0 = (wc & 1) * 64 + lrow;  // B row within its half

  f32x4 acc[8][4] = {};
  bf16x8 af0[2][4], af1[2][4], bl[2][2], bh[2][2];

  // prologue: tile0's 4 halves + tile1's B halves (12 loads);
  // vmcnt(4) certifies tile0 (8 oldest); vmcnt BEFORE barrier.
  stage_half(A, bm,       0, smw,         tid);
  stage_half(A, bm + 128, 0, smw + 16384, tid);
  stage_half(B, bn,       0, smw + 32768, tid);
  stage_half(B, bn + 128, 0, smw + 49152, tid);
  stage_half(B, bn,       BK, smw + 65536 + 32768, tid);
  stage_half(B, bn + 128, BK, smw + 65536 + 49152, tid);
  asm volatile("s_waitcnt vmcnt(4)" ::: "memory");
  __builtin_amdgcn_s_barrier();

#pragma unroll 1
  for (int t = 0; t < NT; ++t) {
    const int cur = t & 1;
    const char* Abuf = smw + cur * 65536 + wr * 16384;
    const char* Bbuf = smw + cur * 65536 + 32768 + (wc >> 1) * 16384;
    char* nbA = smw + (cur ^ 1) * 65536;          // A halves of t+1
    char* cbB = smw + cur * 65536 + 32768;        // B halves of t+2
    const int k1 = (t + 1) * BK, k2 = (t + 2) * BK;
    const bool pf1 = (t + 1 < NT), pf2 = (t + 2 < NT);

    // ---- P1: read af0(8)+bl(4); stage A0(t+1); MFMA q1 ----
    READ_A4(af0, Abuf, 0);
    READ_B2(bl, Bbuf, 0);
    if (pf1) stage_half(A, bm, k1, nbA, tid);
    __builtin_amdgcn_sched_barrier(0);
    __builtin_amdgcn_s_barrier();
    asm volatile("s_waitcnt lgkmcnt(0)" ::: "memory");
    __builtin_amdgcn_sched_barrier(0);
    MFMA_Q(af0, bl, 0, 0);
    __builtin_amdgcn_s_barrier();

    // ---- P2: read bh(4); stage A1(t+1); MFMA q2 ----
    READ_B2(bh, Bbuf, 32);
    if (pf1) stage_half(A, bm + 128, k1, nbA + 16384, tid);
    __builtin_amdgcn_sched_barrier(0);
    __builtin_amdgcn_s_barrier();
    asm volatile("s_waitcnt lgkmcnt(0)" ::: "memory");
    __builtin_amdgcn_sched_barrier(0);
    MFMA_Q(af0, bh, 0, 2);
    __builtin_amdgcn_s_barrier();

    // ---- P3: read af1(8); stage B0(t+2); MFMA q3 ----
    READ_A4(af1, Abuf, 64);
    if (pf2) stage_half(B, bn, k2, cbB, tid);
    __builtin_amdgcn_sched_barrier(0);
    __builtin_amdgcn_s_barrier();
    asm volatile("s_waitcnt lgkmcnt(0)" ::: "memory");
    __builtin_amdgcn_sched_barrier(0);
    MFMA_Q(af1, bl, 4, 0);
    __builtin_amdgcn_s_barrier();

    // ---- P4: stage B1(t+2); MFMA q4; single per-tile cert ----
    if (pf2) stage_half(B, bn + 128, k2, cbB + 16384, tid);
    __builtin_amdgcn_sched_barrier(0);
    __builtin_amdgcn_s_barrier();
    MFMA_Q(af1, bh, 4, 2);
    if (pf2) {
      asm volatile("s_waitcnt vmcnt(4)" ::: "memory");  // tile t+1 complete
      __builtin_amdgcn_s_barrier();
    } else if (pf1) {
      asm volatile("s_waitcnt vmcnt(0)" ::: "memory");  // tail: drain A(NT-1)
      __builtin_amdgcn_s_barrier();
    }
  }

  // epilogue: C/D layout col=lane&15, row=(lane>>4)*4+r  [m89-verified]
  const int orow = bm + wr * 128 + kg * 4;
  const int ocol = bn + wc * 64 + lrow;
#pragma unroll
  for (int n = 0; n < 4; ++n) {
    const float s = scale[ocol + n * 16];
#pragma unroll
    for (int m = 0; m < 8; ++m) {
#pragma unroll
      for (int r = 0; r < 4; ++r)
        out[(size_t)(orow + m * 16 + r) * N_DIM + ocol + n * 16] =
            acc[m][n][r] * s;
    }
  }
}

// ---- fallback (only if ws too small): fp32 LDS-tiled, correct but slow ----
__global__ __launch_bounds__(256) void gemm_fallback(
    const float* __restrict__ X, const int* __restrict__ Wq,
    const float* __restrict__ scale, float* __restrict__ out) {
  __shared__ float Xs[64][17];
  __shared__ float Ws[64][17];
  const int tid = threadIdx.x;
  const int tn = blockIdx.x % (N_DIM / 64);
  const int tm = blockIdx.x / (N_DIM / 64);
  const int tr = tid >> 4, tc = tid & 15;
  float acc[4][4] = {};
  for (int k0 = 0; k0 < K_DIM; k0 += 16) {
#pragma unroll
    for (int i = 0; i < 4; ++i) {
      int idx = tid + i * 256;
      int r = idx >> 4, c = idx & 15;
      Xs[r][c] = X[(size_t)(tm * 64 + r) * K_DIM + k0 + c];
      Ws[r][c] = (float)Wq[(size_t)(tn * 64 + r) * K_DIM + k0 + c];
    }
    __syncthreads();
#pragma unroll
    for (int kk = 0; kk < 16; ++kk)
#pragma unroll
      for (int i = 0; i < 4; ++i) {
        float a = Xs[tr * 4 + i][kk];
#pragma unroll
        for (int j = 0; j < 4; ++j) acc[i][j] += a * Ws[tc * 4 + j][kk];
      }
    __syncthreads();
  }
#pragma unroll
  for (int i = 0; i < 4; ++i)
#pragma unroll
    for (int j = 0; j < 4; ++j) {
      int row = tm * 64 + tr * 4 + i, col = tn * 64 + tc * 4 + j;
      out[(size_t)row * N_DIM + col] = acc[i][j] * scale[col];
    }
}

extern "C" void kernel_launch(void* const* d_in, const int* in_sizes, int n_in,
                              void* d_out, int out_size, void* d_ws, size_t ws_size,
                              hipStream_t stream) {
  const float* x = (const float*)d_in[0];
  const int* Wq = (const int*)d_in[1];
  const float* scale = (const float*)d_in[2];
  float* out = (float*)d_out;

  const size_t XN = (size_t)M_DIM * K_DIM;
  const size_t WN = (size_t)N_DIM * K_DIM;
  const size_t need = (XN + WN) * sizeof(unsigned short);

  if (ws_size >= need) {
    unsigned short* xbf = (unsigned short*)d_ws;
    unsigned short* wbf = xbf + XN;
    cvt_x_kernel<<<(unsigned)(XN / 2048), 256, 0, stream>>>(x, xbf);
    cvt_w_kernel<<<(unsigned)(WN / 2048), 256, 0, stream>>>(Wq, wbf);
    gemm_bf16<<<NWG, 512, 0, stream>>>(xbf, wbf, scale, out);
  } else {
    gemm_fallback<<<(N_DIM / 64) * (M_DIM / 64), 256, 0, stream>>>(x, Wq, scale, out);
  }
}